// Round 1
// baseline (441.886 us; speedup 1.0000x reference)
//
#include <hip/hip_runtime.h>

// 9x9 local-max peak detection (threshold 0.5) on 8192x8192 fp32.
// Separable max-pool via LDS staging:
//   phase 1: global -> LDS 72x72 halo tile (float4, thresholded)
//   phase 2: vertical 9-max -> LDS 64x72
//   phase 3: horizontal 9-max + (mp>0 && mp==center) ? mp : 0 -> global
// 0-padding == -inf padding here: thresholded values are >= 0 and every
// window contains its (in-bounds) center.

#define H 8192
#define W 8192
#define TILE 64
#define HALO 4
#define INW (TILE + 2 * HALO) /* 72 */
#define THRESH 0.5f

__global__ __launch_bounds__(256) void peak9x9_kernel(const float* __restrict__ in,
                                                      float* __restrict__ out) {
    __shared__ float s_in[INW * INW];    // 72x72 thresholded input (20.25 KB)
    __shared__ float s_cm[TILE * INW];   // 64x72 vertical max      (18 KB)

    const int tid  = threadIdx.x;
    const int col0 = blockIdx.x * TILE;
    const int row0 = blockIdx.y * TILE;

    // ---- Phase 1: load 72x72 tile as 72*18 = 1296 aligned float4s ----
    // Halo start col0-4 is a multiple of 4 floats -> every float4 is 16B
    // aligned and is either fully in-bounds or fully out-of-bounds in x.
    for (int i = tid; i < 72 * 18; i += 256) {
        const int rr = i / 18;
        const int f4 = i - rr * 18;
        const int gr = row0 - HALO + rr;
        const int gc = col0 - HALO + f4 * 4;
        float4 v;
        if ((unsigned)gr < (unsigned)H && (unsigned)gc < (unsigned)W) {
            v = *(const float4*)(in + (size_t)gr * W + gc);
        } else {
            v = make_float4(0.f, 0.f, 0.f, 0.f);
        }
        v.x = v.x > THRESH ? v.x : 0.f;
        v.y = v.y > THRESH ? v.y : 0.f;
        v.z = v.z > THRESH ? v.z : 0.f;
        v.w = v.w > THRESH ? v.w : 0.f;
        *(float4*)(&s_in[rr * INW + f4 * 4]) = v;
    }
    __syncthreads();

    // ---- Phase 2: vertical 9-max. s_cm[r][c] = max(s_in[r..r+8][c]) ----
    // 64 threads across columns (conflict-free), each thread owns a 16-row
    // run: 24 LDS reads feed 16 sliding windows from registers.
    {
        const int tx = tid & 63;
        const int ty = tid >> 6;   // 0..3
        const int r0 = ty * 16;
        for (int cc = tx; cc < INW; cc += 64) {
            float v[24];
#pragma unroll
            for (int i = 0; i < 24; ++i) v[i] = s_in[(r0 + i) * INW + cc];
#pragma unroll
            for (int r = 0; r < 16; ++r) {
                float m = v[r];
#pragma unroll
                for (int j = 1; j < 9; ++j) m = fmaxf(m, v[r + j]);
                s_cm[(r0 + r) * INW + cc] = m;
            }
        }
    }
    __syncthreads();

    // ---- Phase 3: horizontal 9-max + peak test, float4 stores ----
    // Thread -> (row rb + 16k, cols c0..c0+3). v[0..11] are cmax cols
    // c0..c0+11; output i has window v[i..i+8]; v[3..8] is shared.
    {
        const int cg = tid & 15;
        const int rb = tid >> 4;   // 0..15
        const int c0 = cg * 4;
#pragma unroll
        for (int k = 0; k < 4; ++k) {
            const int r = rb + k * 16;
            const float4 va = *(const float4*)&s_cm[r * INW + c0];
            const float4 vb = *(const float4*)&s_cm[r * INW + c0 + 4];
            const float4 vc = *(const float4*)&s_cm[r * INW + c0 + 8];
            // common = max(v3..v8)
            const float common = fmaxf(fmaxf(fmaxf(va.w, vb.x), fmaxf(vb.y, vb.z)),
                                       fmaxf(vb.w, vc.x));
            const float m12  = fmaxf(va.y, va.z);   // max(v1,v2)
            const float m910 = fmaxf(vc.y, vc.z);   // max(v9,v10)
            const float o0 = fmaxf(common, fmaxf(va.x, m12));   // v0..v8
            const float o1 = fmaxf(common, fmaxf(m12, vc.y));   // v1..v9
            const float o2 = fmaxf(common, fmaxf(va.z, m910));  // v2..v10
            const float o3 = fmaxf(common, fmaxf(m910, vc.w));  // v3..v11
            const float4 pt = *(const float4*)&s_in[(r + 4) * INW + c0 + 4];
            float4 ov;
            ov.x = (o0 > 0.f && o0 == pt.x) ? o0 : 0.f;
            ov.y = (o1 > 0.f && o1 == pt.y) ? o1 : 0.f;
            ov.z = (o2 > 0.f && o2 == pt.z) ? o2 : 0.f;
            ov.w = (o3 > 0.f && o3 == pt.w) ? o3 : 0.f;
            *(float4*)(out + (size_t)(row0 + r) * W + (col0 + c0)) = ov;
        }
    }
}

extern "C" void kernel_launch(void* const* d_in, const int* in_sizes, int n_in,
                              void* d_out, int out_size, void* d_ws, size_t ws_size,
                              hipStream_t stream) {
    const float* in = (const float*)d_in[0];
    float* out = (float*)d_out;
    dim3 grid(W / TILE, H / TILE);   // 128 x 128 tiles, all full (8192 % 64 == 0)
    peak9x9_kernel<<<grid, dim3(256, 1, 1), 0, stream>>>(in, out);
}

// Round 2
// 440.894 us; speedup vs baseline: 1.0022x; 1.0022x over previous
//
#include <hip/hip_runtime.h>

// 9x9 local-max peak detection (threshold 0.5) on 8192x8192 fp32.
//
// Key identity: threshold t(x)=x*[x>0.5] commutes with max (monotone), so
//   conf[r][c] = (M > 0.5 && M == raw[r][c]) ? M : 0,  M = 9x9 raw max.
// 0-padding is equivalent to -inf padding: a pad value can only win the max
// when everything is <= 0, and then the >0.5 gate kills it anyway.
//
// Streaming structure (no LDS, no barriers):
//   wave = 256-col band (lane owns 4 cols via float4), rolls over 64 output
//   rows. Per input row: 3 overlapping float4 loads (L1 serves the +-16B
//   shifts), horizontal 9-max via shared-prefix, 9-deep register ring,
//   vertical 9-max, predicate, coalesced float4 store. Unroll-by-9 keeps all
//   ring indices compile-time-static (registers, no spills, no v_movs).

#define W 8192
#define H 8192
#define THRESH 0.5f

typedef float v4f __attribute__((ext_vector_type(4)));

__device__ __forceinline__ v4f ld4(const float* __restrict__ in, int r, int c) {
    v4f v = {0.f, 0.f, 0.f, 0.f};
    if ((unsigned)c < (unsigned)W) {
        v = *(const v4f*)(in + (size_t)r * W + c);
    }
    return v;
}

__global__ __launch_bounds__(256, 4) void peak_stream(const float* __restrict__ in,
                                                      float* __restrict__ out) {
    const int lane = threadIdx.x;                       // 0..63
    const int col0 = blockIdx.x * 256 + lane * 4;       // this lane's 4 cols
    const int r0   = (blockIdx.y * 4 + threadIdx.y) * 64; // strip's first output row

    v4f hm[9];   // ring: horizontal 9-max rows rin-8..rin
    v4f ce[9];   // ring: raw center values (delayed 4 rows for the compare)

    // One input row: k = ring slot (compile-time const), rin = input row,
    // emit = produce output row rin-4.
    auto dorow = [&](int rin, int k, bool emit) {
        v4f l = {0.f, 0.f, 0.f, 0.f}, v = l, r = l;
        if ((unsigned)rin < (unsigned)H) {
            l = ld4(in, rin, col0 - 4);
            v = ld4(in, rin, col0);
            r = ld4(in, rin, col0 + 4);
        }
        // L = [l.x l.y l.z l.w v.x v.y v.z v.w r.x r.y r.z r.w]; out j = max L[j..j+8]
        const float common = fmaxf(fmaxf(fmaxf(l.w, v.x), fmaxf(v.y, v.z)),
                                   fmaxf(v.w, r.x));     // max L[3..8]
        const float m12  = fmaxf(l.y, l.z);
        const float m910 = fmaxf(r.y, r.z);
        v4f o;
        o.x = fmaxf(common, fmaxf(l.x, m12));
        o.y = fmaxf(common, fmaxf(m12, r.y));
        o.z = fmaxf(common, fmaxf(l.z, m910));
        o.w = fmaxf(common, fmaxf(m910, r.w));
        hm[k] = o;
        ce[k] = v;
        if (emit) {
            v4f m = hm[0];
#pragma unroll
            for (int j = 1; j < 9; ++j) {
                m.x = fmaxf(m.x, hm[j].x);
                m.y = fmaxf(m.y, hm[j].y);
                m.z = fmaxf(m.z, hm[j].z);
                m.w = fmaxf(m.w, hm[j].w);
            }
            const v4f c4 = ce[(k + 5) % 9];  // raw value at row rin-4
            v4f ov;
            ov.x = (m.x > THRESH && m.x == c4.x) ? m.x : 0.f;
            ov.y = (m.y > THRESH && m.y == c4.y) ? m.y : 0.f;
            ov.z = (m.z > THRESH && m.z == c4.z) ? m.z : 0.f;
            ov.w = (m.w > THRESH && m.w == c4.w) ? m.w : 0.f;
            const int rout = rin - 4;
            *(v4f*)(out + (size_t)rout * W + col0) = ov;
        }
    };

    // Prologue: fill the ring (input rows r0-4 .. r0+4); k=8 emits row r0.
#pragma unroll
    for (int t = 0; t < 9; ++t) {
        dorow(r0 - 4 + t, t, t >= 8);
    }
    // Main: 7 chunks of 9 rows, every iteration emits. tc % 9 == 0 so the
    // ring slot is exactly k (static).
    for (int tc = 9; tc < 72; tc += 9) {
#pragma unroll
        for (int k = 0; k < 9; ++k) {
            dorow(r0 - 4 + tc + k, k, true);
        }
    }
}

extern "C" void kernel_launch(void* const* d_in, const int* in_sizes, int n_in,
                              void* d_out, int out_size, void* d_ws, size_t ws_size,
                              hipStream_t stream) {
    const float* in = (const float*)d_in[0];
    float* out = (float*)d_out;
    dim3 grid(W / 256, H / 256);        // 32 x 32 blocks
    dim3 block(64, 4, 1);               // 4 waves; wave ty handles strip 4*by+ty
    peak_stream<<<grid, block, 0, stream>>>(in, out);
}